// Round 2
// baseline (855.739 us; speedup 1.0000x reference)
//
#include <hip/hip_runtime.h>
#include <math.h>

typedef __attribute__((ext_vector_type(8))) __bf16 bf16x8;
typedef __attribute__((ext_vector_type(4))) __bf16 bf16x4;
typedef __attribute__((ext_vector_type(2))) __bf16 bf16x2;
typedef __attribute__((ext_vector_type(4))) float f32x4;

#define MFMA16(a, b, c) __builtin_amdgcn_mfma_f32_16x16x32_bf16(a, b, c, 0, 0, 0)

// ---------------------------------------------------------------- pack fp32->bf16
__global__ void pack_bf16(const float* __restrict__ src, __bf16* __restrict__ dst, int n4) {
    int idx = blockIdx.x * 256 + threadIdx.x;
    if (idx < n4) {
        float4 f = *(const float4*)(src + (size_t)idx * 4);
        bf16x4 o;
        o.x = (__bf16)f.x; o.y = (__bf16)f.y; o.z = (__bf16)f.z; o.w = (__bf16)f.w;
        *(bf16x4*)(dst + (size_t)idx * 4) = o;
    }
}

// ---------------------------------------------------------------- GEMM: C[m][n] = sum_k A[m][k]*B[n][k] + bias[n]
// A: MxK bf16 row-major. B: NxK bf16 row-major. C: MxN (fp32 or bf16).
template <typename OutT>
__global__ void gemm_bt_bias(const __bf16* __restrict__ A, const __bf16* __restrict__ B,
                             const float* __restrict__ bias, OutT* __restrict__ C,
                             int M, int N, int K) {
    __shared__ __align__(16) __bf16 As[128 * 72];  // stride 72 bf16 = 144B (16B-mult)
    __shared__ __align__(16) __bf16 Bs[128 * 72];
    const int tid = threadIdx.x;
    const int lane = tid & 63, wave = tid >> 6;
    const int lm = lane & 15, q8 = (lane >> 4) * 8, quad = lane >> 4;
    const int wr = wave >> 1, wc = wave & 1;
    const int n0 = blockIdx.x * 128, m0 = blockIdx.y * 128;

    f32x4 acc[4][4] = {};

    for (int k0 = 0; k0 < K; k0 += 64) {
        __syncthreads();
        for (int r = 0; r < 4; ++r) {
            int c = r * 256 + tid;              // 0..1023
            int row = c >> 3, ch = (c & 7) * 8; // 128 rows x 8 chunks covers k 0..63
            uint4 ga = *(const uint4*)(A + (size_t)(m0 + row) * K + k0 + ch);
            uint4 gb = *(const uint4*)(B + (size_t)(n0 + row) * K + k0 + ch);
            *(uint4*)(As + row * 72 + ch) = ga;
            *(uint4*)(Bs + row * 72 + ch) = gb;
        }
        __syncthreads();
        for (int kk = 0; kk < 64; kk += 32) {
            bf16x8 a[4], b[4];
            for (int i = 0; i < 4; ++i)
                a[i] = *(const bf16x8*)(As + (wr * 64 + i * 16 + lm) * 72 + kk + q8);
            for (int j = 0; j < 4; ++j)
                b[j] = *(const bf16x8*)(Bs + (wc * 64 + j * 16 + lm) * 72 + kk + q8);
            for (int i = 0; i < 4; ++i)
                for (int j = 0; j < 4; ++j)
                    acc[i][j] = MFMA16(a[i], b[j], acc[i][j]);
        }
    }
    for (int j = 0; j < 4; ++j) {
        int col = n0 + wc * 64 + j * 16 + lm;
        float bj = bias[col];
        for (int i = 0; i < 4; ++i) {
            int mb = m0 + wr * 64 + i * 16 + quad * 4;
            for (int r = 0; r < 4; ++r)
                C[(size_t)(mb + r) * N + col] = (OutT)(acc[i][j][r] + bj);
        }
    }
}

// ---------------------------------------------------------------- RMSNorm + 3D RoPE on q,k (in place, bf16)
// qkv: [4096][9216] bf16 (q at h*128, k at 3072+h*128).
__global__ void rmsrope(__bf16* __restrict__ qkv, const float* __restrict__ qw,
                        const float* __restrict__ kw) {
    int bn = blockIdx.x;            // b*2048 + n
    int n = bn & 2047;
    int tid = threadIdx.x, wave = tid >> 6, lane = tid & 63;
    int d0 = lane * 2;
    // 3D rope: n -> (t, hp, wp); d0 -> section
    int t = n >> 8, hp = (n >> 4) & 15, wp = n & 15;
    float pos, fi;
    if (d0 < 44)      { pos = (float)t;  fi = (float)(d0 >> 1) * (2.0f / 44.0f); }
    else if (d0 < 86) { pos = (float)hp; fi = (float)((d0 - 44) >> 1) * (2.0f / 42.0f); }
    else              { pos = (float)wp; fi = (float)((d0 - 86) >> 1) * (2.0f / 42.0f); }
    float freq = expf(-fi * 9.210340371976184f);  // 10000^-fi
    float ang = pos * freq, sn, cs;
    sincosf(ang, &sn, &cs);
    float w0q = qw[d0], w1q = qw[d0 + 1], w0k = kw[d0], w1k = kw[d0 + 1];

    for (int h = wave; h < 24; h += 4) {
        size_t base = (size_t)bn * 9216 + h * 128 + d0;
        // q
        {
            bf16x2 xv = *(bf16x2*)(qkv + base);
            float x0 = (float)xv.x, x1 = (float)xv.y;
            float ss = x0 * x0 + x1 * x1;
            for (int m = 1; m < 64; m <<= 1) ss += __shfl_xor(ss, m, 64);
            float rr = rsqrtf(ss * (1.0f / 128.0f) + 1e-6f);
            float y0 = x0 * rr * w0q, y1 = x1 * rr * w1q;
            bf16x2 st; st.x = (__bf16)(y0 * cs - y1 * sn); st.y = (__bf16)(y1 * cs + y0 * sn);
            *(bf16x2*)(qkv + base) = st;
        }
        // k
        {
            bf16x2 xv = *(bf16x2*)(qkv + base + 3072);
            float x0 = (float)xv.x, x1 = (float)xv.y;
            float ss = x0 * x0 + x1 * x1;
            for (int m = 1; m < 64; m <<= 1) ss += __shfl_xor(ss, m, 64);
            float rr = rsqrtf(ss * (1.0f / 128.0f) + 1e-6f);
            float y0 = x0 * rr * w0k, y1 = x1 * rr * w1k;
            bf16x2 st; st.x = (__bf16)(y0 * cs - y1 * sn); st.y = (__bf16)(y1 * cs + y0 * sn);
            *(bf16x2*)(qkv + base + 3072) = st;
        }
    }
}

// ---------------------------------------------------------------- flash attention
// qkv: [4096][9216] bf16 (q/k roped+normed in place; v at 6144+h*128).
// O: [B][N][C] bf16.
__global__ __launch_bounds__(256, 2)
void flash(const __bf16* __restrict__ qkv, __bf16* __restrict__ Oo) {
    __shared__ __align__(16) __bf16 Ks[64 * 136];   // [key][d]
    __shared__ __align__(16) __bf16 VTs[128 * 72];  // [d][key]
    __shared__ __align__(16) __bf16 Ps[128 * 72];   // [q row][key]
    int bh = blockIdx.x >> 4, qt = blockIdx.x & 15;
    int b = bh / 24, h = bh % 24;
    int q0 = qt * 128;
    int tid = threadIdx.x, wave = tid >> 6, lane = tid & 63;
    int lm = lane & 15, q8 = (lane >> 4) * 8, quad = lane >> 4;
    int wb = wave * 32;
    const float sc = 0.08838834764831845f;  // 1/sqrt(128)

    // Q fragments (rows wb..wb+31 of this q-tile)
    bf16x8 qf[2][4];
    for (int i = 0; i < 2; ++i)
        for (int kk = 0; kk < 4; ++kk)
            qf[i][kk] = *(const bf16x8*)(qkv + (size_t)(b * 2048 + q0 + wb + i * 16 + lm) * 9216
                                         + h * 128 + kk * 32 + q8);

    float mrow[2][4], lrow[2][4];
    f32x4 oacc[2][8] = {};
    for (int i = 0; i < 2; ++i)
        for (int r = 0; r < 4; ++r) { mrow[i][r] = -__builtin_inff(); lrow[i][r] = 0.f; }

    for (int nt = 0; nt < 32; ++nt) {
        int n0 = nt * 64;
        __syncthreads();
        for (int r = 0; r < 4; ++r) {
            int c = r * 256 + tid;                  // 0..1023
            // K: [64 key][128 d], coalesced both sides
            int krow = c >> 4, kch = (c & 15) * 8;  // 64 x 16 chunks
            *(uint4*)(Ks + krow * 136 + kch) =
                *(const uint4*)(qkv + (size_t)(b * 2048 + n0 + krow) * 9216 + 3072 + h * 128 + kch);
            // V: read [key][d] rows, write transposed [d][key]
            int vkey = c & 63, vch = (c >> 6) * 8;  // lanes differ in key -> conflict-free LDS writes
            bf16x8 vv = *(const bf16x8*)(qkv + (size_t)(b * 2048 + n0 + vkey) * 9216 + 6144 + h * 128 + vch);
            for (int j = 0; j < 8; ++j)
                VTs[(vch + j) * 72 + vkey] = vv[j];
        }
        __syncthreads();

        // S = Q K^T
        f32x4 s[2][4] = {};
        for (int kk = 0; kk < 4; ++kk) {
            bf16x8 bk[4];
            for (int j = 0; j < 4; ++j)
                bk[j] = *(const bf16x8*)(Ks + (j * 16 + lm) * 136 + kk * 32 + q8);
            for (int i = 0; i < 2; ++i)
                for (int j = 0; j < 4; ++j)
                    s[i][j] = MFMA16(qf[i][kk], bk[j], s[i][j]);
        }
        // online softmax (each row lives in 16 lanes sharing a quad)
        for (int i = 0; i < 2; ++i) {
            for (int r = 0; r < 4; ++r) {
                float v0 = s[i][0][r] * sc, v1 = s[i][1][r] * sc;
                float v2 = s[i][2][r] * sc, v3 = s[i][3][r] * sc;
                float mx = fmaxf(fmaxf(v0, v1), fmaxf(v2, v3));
                for (int msk = 1; msk < 16; msk <<= 1) mx = fmaxf(mx, __shfl_xor(mx, msk, 64));
                float mn = fmaxf(mrow[i][r], mx);
                float alpha = __expf(mrow[i][r] - mn);
                float p0 = __expf(v0 - mn), p1 = __expf(v1 - mn);
                float p2 = __expf(v2 - mn), p3 = __expf(v3 - mn);
                float rs = p0 + p1 + p2 + p3;
                for (int msk = 1; msk < 16; msk <<= 1) rs += __shfl_xor(rs, msk, 64);
                lrow[i][r] = lrow[i][r] * alpha + rs;
                mrow[i][r] = mn;
                for (int ct = 0; ct < 8; ++ct) oacc[i][ct][r] *= alpha;
                int prow = wb + i * 16 + quad * 4 + r;
                Ps[prow * 72 + 0  + lm] = (__bf16)p0;
                Ps[prow * 72 + 16 + lm] = (__bf16)p1;
                Ps[prow * 72 + 32 + lm] = (__bf16)p2;
                Ps[prow * 72 + 48 + lm] = (__bf16)p3;
            }
        }
        // O += P V (P rows are wave-private; no cross-wave barrier needed)
        for (int kk = 0; kk < 2; ++kk) {
            bf16x8 ap[2];
            for (int i = 0; i < 2; ++i)
                ap[i] = *(const bf16x8*)(Ps + (wb + i * 16 + lm) * 72 + kk * 32 + q8);
            for (int ct = 0; ct < 8; ++ct) {
                bf16x8 bv = *(const bf16x8*)(VTs + (ct * 16 + lm) * 72 + kk * 32 + q8);
                for (int i = 0; i < 2; ++i)
                    oacc[i][ct] = MFMA16(ap[i], bv, oacc[i][ct]);
            }
        }
    }
    // epilogue: O /= l, write [B][N][H*D] bf16
    for (int i = 0; i < 2; ++i) {
        for (int r = 0; r < 4; ++r) {
            float inv = 1.0f / lrow[i][r];
            int row = q0 + wb + i * 16 + quad * 4 + r;
            size_t base = ((size_t)b * 2048 + row) * 3072 + h * 128;
            for (int ct = 0; ct < 8; ++ct)
                Oo[base + ct * 16 + lm] = (__bf16)(oacc[i][ct][r] * inv);
        }
    }
}

// ---------------------------------------------------------------- launch
extern "C" void kernel_launch(void* const* d_in, const int* in_sizes, int n_in,
                              void* d_out, int out_size, void* d_ws, size_t ws_size,
                              hipStream_t stream) {
    const float* x      = (const float*)d_in[0];
    const float* qkv_w  = (const float*)d_in[1];
    const float* qkv_b  = (const float*)d_in[2];
    const float* qnw    = (const float*)d_in[3];
    const float* knw    = (const float*)d_in[4];
    const float* proj_w = (const float*)d_in[5];
    const float* proj_b = (const float*)d_in[6];
    float* out = (float*)d_out;
    char* ws = (char*)d_ws;

    // ws layout (bytes), total 176,160,768
    __bf16* xb   = (__bf16*)(ws + 0);           //  25,165,824  x bf16 [4096][3072] (dead after gemm1)
    __bf16* attn = (__bf16*)(ws + 0);           //  alias: flash output [4096][3072] bf16
    __bf16* w1b  = (__bf16*)(ws + 25165824);    //  56,623,104  qkv_w bf16
    __bf16* w2b  = (__bf16*)(ws + 81788928);    //  18,874,368  proj_w bf16
    __bf16* qkvb = (__bf16*)(ws + 100663296);   //  75,497,472  qkv bf16 [4096][9216]

    pack_bf16<<<12288, 256, 0, stream>>>(x, xb, 3145728);
    pack_bf16<<<27648, 256, 0, stream>>>(qkv_w, w1b, 7077888);
    pack_bf16<<<9216, 256, 0, stream>>>(proj_w, w2b, 2359296);

    gemm_bt_bias<__bf16><<<dim3(72, 32), 256, 0, stream>>>(xb, w1b, qkv_b, qkvb, 4096, 9216, 3072);

    rmsrope<<<4096, 256, 0, stream>>>(qkvb, qnw, knw);

    flash<<<768, 256, 0, stream>>>(qkvb, attn);

    gemm_bt_bias<float><<<dim3(24, 32), 256, 0, stream>>>(attn, w2b, proj_b, out, 4096, 3072, 3072);
}

// Round 3
// 795.593 us; speedup vs baseline: 1.0756x; 1.0756x over previous
//
#include <hip/hip_runtime.h>
#include <math.h>

typedef __attribute__((ext_vector_type(8))) __bf16 bf16x8;
typedef __attribute__((ext_vector_type(4))) __bf16 bf16x4;
typedef __attribute__((ext_vector_type(2))) __bf16 bf16x2;
typedef __attribute__((ext_vector_type(4))) float f32x4;

#define MFMA16(a, b, c) __builtin_amdgcn_mfma_f32_16x16x32_bf16(a, b, c, 0, 0, 0)

typedef const __attribute__((address_space(1))) unsigned int* gas_t;
typedef __attribute__((address_space(3))) unsigned int* las_t;

__device__ __forceinline__ void g2lds16(const __bf16* g, __bf16* l) {
    __builtin_amdgcn_global_load_lds((gas_t)(const void*)g, (las_t)(void*)l, 16, 0, 0);
}

// ---------------------------------------------------------------- pack fp32->bf16
__global__ void pack_bf16(const float* __restrict__ src, __bf16* __restrict__ dst, int n4) {
    int idx = blockIdx.x * 256 + threadIdx.x;
    if (idx < n4) {
        float4 f = *(const float4*)(src + (size_t)idx * 4);
        bf16x4 o;
        o.x = (__bf16)f.x; o.y = (__bf16)f.y; o.z = (__bf16)f.z; o.w = (__bf16)f.w;
        *(bf16x4*)(dst + (size_t)idx * 4) = o;
    }
}

// ---------------------------------------------------------------- GEMM (m97 structure): C = A·B^T + bias
// A: MxK bf16 row-major. B: NxK bf16 row-major. C: MxN.
template <typename OutT>
__global__ void gemm_bt_bias(const __bf16* __restrict__ A, const __bf16* __restrict__ B,
                             const float* __restrict__ bias, OutT* __restrict__ C,
                             int M, int N, int K) {
    __shared__ __align__(16) __bf16 As[128 * 64];  // unpadded: global_load_lds needs lane-contiguous dest
    __shared__ __align__(16) __bf16 Bs[128 * 64];
    const int tid = threadIdx.x;
    const int lane = tid & 63, wave = tid >> 6;
    const int lm = lane & 15, q8 = (lane >> 4) * 8, quad = lane >> 4;
    const int wr = wave >> 1, wc = wave & 1;
    const int n0 = blockIdx.x * 128, m0 = blockIdx.y * 128;

    f32x4 acc[4][4] = {};

    for (int k0 = 0; k0 < K; k0 += 64) {
        __syncthreads();
        for (int it = 0; it < 4; ++it) {
            int c = it * 256 + tid;               // 0..1023: chunk of 8 bf16
            int row = c >> 3, ch = (c & 7) * 8;   // LDS elem offset row*64+ch == c*8 (lane-contiguous)
            g2lds16(A + (size_t)(m0 + row) * K + k0 + ch, As + c * 8);
            g2lds16(B + (size_t)(n0 + row) * K + k0 + ch, Bs + c * 8);
        }
        __syncthreads();   // drains vmcnt for global_load_lds
        for (int kk = 0; kk < 64; kk += 32) {
            bf16x8 a[4], b[4];
            for (int i = 0; i < 4; ++i)
                a[i] = *(const bf16x8*)(As + (wr * 64 + i * 16 + lm) * 64 + kk + q8);
            for (int j = 0; j < 4; ++j)
                b[j] = *(const bf16x8*)(Bs + (wc * 64 + j * 16 + lm) * 64 + kk + q8);
            for (int i = 0; i < 4; ++i)
                for (int j = 0; j < 4; ++j)
                    acc[i][j] = MFMA16(a[i], b[j], acc[i][j]);
        }
    }
    for (int j = 0; j < 4; ++j) {
        int col = n0 + wc * 64 + j * 16 + lm;
        float bj = bias[col];
        for (int i = 0; i < 4; ++i) {
            int mb = m0 + wr * 64 + i * 16 + quad * 4;
            for (int r = 0; r < 4; ++r)
                C[(size_t)(mb + r) * N + col] = (OutT)(acc[i][j][r] + bj);
        }
    }
}

// ---------------------------------------------------------------- RMSNorm + 3D RoPE on q,k (in place, bf16)
__global__ void rmsrope(__bf16* __restrict__ qkv, const float* __restrict__ qw,
                        const float* __restrict__ kw) {
    int bn = blockIdx.x;            // b*2048 + n
    int n = bn & 2047;
    int tid = threadIdx.x, wave = tid >> 6, lane = tid & 63;
    int d0 = lane * 2;
    int t = n >> 8, hp = (n >> 4) & 15, wp = n & 15;
    float pos, fi;
    if (d0 < 44)      { pos = (float)t;  fi = (float)(d0 >> 1) * (2.0f / 44.0f); }
    else if (d0 < 86) { pos = (float)hp; fi = (float)((d0 - 44) >> 1) * (2.0f / 42.0f); }
    else              { pos = (float)wp; fi = (float)((d0 - 86) >> 1) * (2.0f / 42.0f); }
    float freq = expf(-fi * 9.210340371976184f);  // 10000^-fi
    float ang = pos * freq, sn, cs;
    sincosf(ang, &sn, &cs);
    float w0q = qw[d0], w1q = qw[d0 + 1], w0k = kw[d0], w1k = kw[d0 + 1];

    for (int h = wave; h < 24; h += 4) {
        size_t base = (size_t)bn * 9216 + h * 128 + d0;
        {
            bf16x2 xv = *(bf16x2*)(qkv + base);
            float x0 = (float)xv.x, x1 = (float)xv.y;
            float ss = x0 * x0 + x1 * x1;
            for (int m = 1; m < 64; m <<= 1) ss += __shfl_xor(ss, m, 64);
            float rr = rsqrtf(ss * (1.0f / 128.0f) + 1e-6f);
            float y0 = x0 * rr * w0q, y1 = x1 * rr * w1q;
            bf16x2 st; st.x = (__bf16)(y0 * cs - y1 * sn); st.y = (__bf16)(y1 * cs + y0 * sn);
            *(bf16x2*)(qkv + base) = st;
        }
        {
            bf16x2 xv = *(bf16x2*)(qkv + base + 3072);
            float x0 = (float)xv.x, x1 = (float)xv.y;
            float ss = x0 * x0 + x1 * x1;
            for (int m = 1; m < 64; m <<= 1) ss += __shfl_xor(ss, m, 64);
            float rr = rsqrtf(ss * (1.0f / 128.0f) + 1e-6f);
            float y0 = x0 * rr * w0k, y1 = x1 * rr * w1k;
            bf16x2 st; st.x = (__bf16)(y0 * cs - y1 * sn); st.y = (__bf16)(y1 * cs + y0 * sn);
            *(bf16x2*)(qkv + base + 3072) = st;
        }
    }
}

// ---------------------------------------------------------------- flash attention (S^T orientation)
// qkv: [4096][9216] bf16 (q/k normed+roped in place; v at 6144+h*128). O: [B][N][C] bf16.
// S^T = K·Q^T: lane holds qrow = lane&15, keys = quad*4+reg (+16j) -> per-lane softmax stats.
__global__ __launch_bounds__(256, 2)
void flash(const __bf16* __restrict__ qkv, __bf16* __restrict__ Oo) {
    __shared__ __align__(16) __bf16 Ks[64 * 136];   // [key][d]
    __shared__ __align__(16) __bf16 VTs[128 * 72];  // [d][key]
    __shared__ __align__(16) __bf16 Ps[128 * 72];   // [q row][key]
    int bh = blockIdx.x >> 4, qt = blockIdx.x & 15;
    int b = bh / 24, h = bh % 24;
    int q0 = qt * 128;
    int tid = threadIdx.x, wave = tid >> 6, lane = tid & 63;
    int lm = lane & 15, q8 = (lane >> 4) * 8, quad = lane >> 4;
    int wb = wave * 32;
    const float sc = 0.08838834764831845f;  // 1/sqrt(128)

    // Q fragments: rows wb+i*16+lm of this q-tile (used as MFMA B operand)
    bf16x8 qf[2][4];
    for (int i = 0; i < 2; ++i)
        for (int kk = 0; kk < 4; ++kk)
            qf[i][kk] = *(const bf16x8*)(qkv + (size_t)(b * 2048 + q0 + wb + i * 16 + lm) * 9216
                                         + h * 128 + kk * 32 + q8);

    float mrow[2] = {-__builtin_inff(), -__builtin_inff()};
    float lrow[2] = {0.f, 0.f};
    f32x4 oacc[2][8] = {};   // oacc[i][ct]: d = ct*16+quad*4+reg, qrow = wb+i*16+lm

    for (int nt = 0; nt < 32; ++nt) {
        int n0 = nt * 64;
        __syncthreads();
        for (int r = 0; r < 4; ++r) {
            int c = r * 256 + tid;                  // 0..1023
            int krow = c >> 4, kch = (c & 15) * 8;  // K: 64 x 16 chunks
            *(uint4*)(Ks + krow * 136 + kch) =
                *(const uint4*)(qkv + (size_t)(b * 2048 + n0 + krow) * 9216 + 3072 + h * 128 + kch);
            int vkey = c & 63, vch = (c >> 6) * 8;  // V: transpose on stage
            bf16x8 vv = *(const bf16x8*)(qkv + (size_t)(b * 2048 + n0 + vkey) * 9216 + 6144 + h * 128 + vch);
            for (int j = 0; j < 8; ++j)
                VTs[(vch + j) * 72 + vkey] = vv[j];
        }
        __syncthreads();

        // S^T = K Q^T : s[i][j] holds keys j*16+quad*4+reg for qrow wb+i*16+lm
        f32x4 s[2][4] = {};
        for (int kk = 0; kk < 4; ++kk) {
            bf16x8 bk[4];
            for (int j = 0; j < 4; ++j)
                bk[j] = *(const bf16x8*)(Ks + (j * 16 + lm) * 136 + kk * 32 + q8);
            for (int i = 0; i < 2; ++i)
                for (int j = 0; j < 4; ++j)
                    s[i][j] = MFMA16(bk[j], qf[i][kk], s[i][j]);
        }
        // online softmax: all 16 key-values for a row are in-lane; cross-quad = 2 shuffles
        for (int i = 0; i < 2; ++i) {
            float mx = -__builtin_inff();
            for (int j = 0; j < 4; ++j)
                for (int r = 0; r < 4; ++r)
                    mx = fmaxf(mx, s[i][j][r]);
            mx *= sc;
            mx = fmaxf(mx, __shfl_xor(mx, 16, 64));
            mx = fmaxf(mx, __shfl_xor(mx, 32, 64));
            float mn = fmaxf(mrow[i], mx);
            float alpha = __expf(mrow[i] - mn);
            mrow[i] = mn;
            float rs = 0.f;
            for (int j = 0; j < 4; ++j) {
                bf16x4 pw;
                for (int r = 0; r < 4; ++r) {
                    float p = __expf(s[i][j][r] * sc - mn);
                    rs += p;
                    pw[r] = (__bf16)p;
                }
                *(bf16x4*)(Ps + (wb + i * 16 + lm) * 72 + j * 16 + quad * 4) = pw;
            }
            rs += __shfl_xor(rs, 16, 64);
            rs += __shfl_xor(rs, 32, 64);
            lrow[i] = lrow[i] * alpha + rs;
            if (__any(alpha != 1.0f))
                for (int ct = 0; ct < 8; ++ct) oacc[i][ct] *= alpha;
        }
        // O^T += V^T P^T (P rows wb..wb+31 are wave-private)
        for (int kk = 0; kk < 2; ++kk) {
            bf16x8 ap[2];
            for (int i = 0; i < 2; ++i)
                ap[i] = *(const bf16x8*)(Ps + (wb + i * 16 + lm) * 72 + kk * 32 + q8);
            for (int ct = 0; ct < 8; ++ct) {
                bf16x8 bv = *(const bf16x8*)(VTs + (ct * 16 + lm) * 72 + kk * 32 + q8);
                for (int i = 0; i < 2; ++i)
                    oacc[i][ct] = MFMA16(bv, ap[i], oacc[i][ct]);
            }
        }
    }
    // epilogue: O /= l; lane owns qrow = wb+i*16+lm, d = ct*16+quad*4+[0..3]
    for (int i = 0; i < 2; ++i) {
        float inv = 1.0f / lrow[i];
        int row = q0 + wb + i * 16 + lm;
        size_t base = ((size_t)b * 2048 + row) * 3072 + h * 128 + quad * 4;
        for (int ct = 0; ct < 8; ++ct) {
            bf16x4 ov;
            for (int r = 0; r < 4; ++r) ov[r] = (__bf16)(oacc[i][ct][r] * inv);
            *(bf16x4*)(Oo + base + ct * 16) = ov;
        }
    }
}

// ---------------------------------------------------------------- launch
extern "C" void kernel_launch(void* const* d_in, const int* in_sizes, int n_in,
                              void* d_out, int out_size, void* d_ws, size_t ws_size,
                              hipStream_t stream) {
    const float* x      = (const float*)d_in[0];
    const float* qkv_w  = (const float*)d_in[1];
    const float* qkv_b  = (const float*)d_in[2];
    const float* qnw    = (const float*)d_in[3];
    const float* knw    = (const float*)d_in[4];
    const float* proj_w = (const float*)d_in[5];
    const float* proj_b = (const float*)d_in[6];
    float* out = (float*)d_out;
    char* ws = (char*)d_ws;

    // ws layout (bytes), total 176,160,768
    __bf16* xb   = (__bf16*)(ws + 0);           //  25,165,824  x bf16 (dead after gemm1)
    __bf16* attn = (__bf16*)(ws + 0);           //  alias: flash output [4096][3072] bf16
    __bf16* w1b  = (__bf16*)(ws + 25165824);    //  56,623,104  qkv_w bf16
    __bf16* w2b  = (__bf16*)(ws + 81788928);    //  18,874,368  proj_w bf16
    __bf16* qkvb = (__bf16*)(ws + 100663296);   //  75,497,472  qkv bf16 [4096][9216]

    pack_bf16<<<12288, 256, 0, stream>>>(x, xb, 3145728);
    pack_bf16<<<27648, 256, 0, stream>>>(qkv_w, w1b, 7077888);
    pack_bf16<<<9216, 256, 0, stream>>>(proj_w, w2b, 2359296);

    gemm_bt_bias<__bf16><<<dim3(72, 32), 256, 0, stream>>>(xb, w1b, qkv_b, qkvb, 4096, 9216, 3072);

    rmsrope<<<4096, 256, 0, stream>>>(qkvb, qnw, knw);

    flash<<<768, 256, 0, stream>>>(qkvb, attn);

    gemm_bt_bias<float><<<dim3(24, 32), 256, 0, stream>>>(attn, w2b, proj_b, out, 4096, 3072, 3072);
}